// Round 1
// baseline (110.495 us; speedup 1.0000x reference)
//
#include <hip/hip_runtime.h>

// Fast HW transcendentals (v_exp_f32 / v_log_f32 / v_rcp_f32), with fallbacks.
#if __has_builtin(__builtin_amdgcn_exp2f)
#define FAST_EXP2(x) __builtin_amdgcn_exp2f(x)
#else
#define FAST_EXP2(x) exp2f(x)
#endif
#if __has_builtin(__builtin_amdgcn_logf)
#define FAST_LOG2(x) __builtin_amdgcn_logf(x)
#else
#define FAST_LOG2(x) log2f(x)
#endif
#if __has_builtin(__builtin_amdgcn_rcpf)
#define FAST_RCP(x) __builtin_amdgcn_rcpf(x)
#else
#define FAST_RCP(x) (1.0f / (x))
#endif

#define LOG2E 1.44269504088896340736f

__device__ __forceinline__ float fast_tanh(float v) {
    // tanh(v) = 1 - 2/(e^{2v}+1);  e^{2v} = 2^{2v*log2e}
    float e = FAST_EXP2(v * (2.0f * LOG2E));
    return fmaf(-2.0f, FAST_RCP(e + 1.0f), 1.0f);
}

__device__ __forceinline__ float fast_sigmoid(float v) {
    return FAST_RCP(1.0f + FAST_EXP2(-v * LOG2E));
}

__global__ __launch_bounds__(256) void subsurf_kernel(
    const float* __restrict__ x, const float* __restrict__ S1,
    const float* __restrict__ W1, const float* __restrict__ b1,
    const float* __restrict__ W2, const float* __restrict__ b2,
    const float* __restrict__ W3, const float* __restrict__ b3,
    float* __restrict__ out, int n)
{
    int i = blockIdx.x * blockDim.x + threadIdx.x;
    if (i >= n) return;

    // Coalesced 16B/lane load of the 4 features.
    float4 xv = ((const float4*)x)[i];
    float xs[4] = {xv.x, xv.y, xv.z, xv.w};
    float s1 = S1[i];

    // Bit-match numpy f32 constant arithmetic for lows / (highs - lows).
    const float lows[3]   = {100.0f, 0.01f, 0.01f};
    const float ranges[3] = {500.0f - 100.0f, 100.0f - 0.01f, 10.0f - 0.01f};

    float vals[3];
    #pragma unroll
    for (int k = 0; k < 3; ++k) {
        float h1[6];
        #pragma unroll
        for (int j = 0; j < 6; ++j) {
            float acc = b1[k * 6 + j];
            #pragma unroll
            for (int d = 0; d < 4; ++d)
                acc = fmaf(xs[d], W1[(k * 4 + d) * 6 + j], acc);
            h1[j] = fast_tanh(acc);
        }
        float h2[6];
        #pragma unroll
        for (int j = 0; j < 6; ++j) {
            float acc = b2[k * 6 + j];
            #pragma unroll
            for (int w = 0; w < 6; ++w)
                acc = fmaf(h1[w], W2[(k * 6 + w) * 6 + j], acc);
            h2[j] = fast_tanh(acc);
        }
        float y = b3[k];
        #pragma unroll
        for (int v = 0; v < 6; ++v)
            y = fmaf(h2[v], W3[k * 6 + v], y);
        vals[k] = fmaf(ranges[k], fast_sigmoid(y), lows[k]);
    }

    float S1max = vals[0], ks = vals[1], nexp = vals[2];
    // (S1/S1max)^n in log2 domain: handles S1==0 (log2->-inf, exp2->0).
    float lr = FAST_LOG2(s1) - FAST_LOG2(S1max);
    float flow = ks * FAST_EXP2(nexp * lr);
    flow = fminf(fmaxf(flow, 0.0f), S1max);
    out[i] = flow;
}

extern "C" void kernel_launch(void* const* d_in, const int* in_sizes, int n_in,
                              void* d_out, int out_size, void* d_ws, size_t ws_size,
                              hipStream_t stream) {
    const float* x  = (const float*)d_in[0];
    const float* S1 = (const float*)d_in[1];
    const float* W1 = (const float*)d_in[2];
    const float* b1 = (const float*)d_in[3];
    const float* W2 = (const float*)d_in[4];
    const float* b2 = (const float*)d_in[5];
    const float* W3 = (const float*)d_in[6];
    const float* b3 = (const float*)d_in[7];
    float* out = (float*)d_out;

    int n = out_size;  // N = 2,000,000 rows, one output per row
    int block = 256;
    int grid = (n + block - 1) / block;
    subsurf_kernel<<<grid, block, 0, stream>>>(x, S1, W1, b1, W2, b2, W3, b3, out, n);
}